// Round 2
// 75.688 us; speedup vs baseline: 1.0129x; 1.0129x over previous
//
#include <hip/hip_runtime.h>
#include <math.h>

#define BIG 1e30f
#define RT10 0.31622776601683794f

// QAM-16 gray-coded points, normalized by 1/sqrt(10).
// real: sign=(i>>3)&1, mag=(i>>1)&1 -> +-{1,3}/sqrt(10)
// imag: sign=(i>>2)&1, mag=(i>>0)&1
__device__ __forceinline__ constexpr float QR(int i) {
    return ((((i >> 3) & 1) ? -1.0f : 1.0f) * ((((i >> 1) & 1) ? 3.0f : 1.0f)) * RT10);
}
__device__ __forceinline__ constexpr float QI(int i) {
    return ((((i >> 2) & 1) ? -1.0f : 1.0f) * (((i & 1) ? 3.0f : 1.0f)) * RT10);
}

// One WAVE per batch (4 batches per 256-thread block). Phase 1: 64-lane
// cooperative complex Cholesky + forward solve of 4 RHS. Phase 2: lane =
// (a<<4)|i1 owns i0 in {a, a+4, a+8, a+12} (q loop); the 16-point i2 sweep
// is SEPARABLE: d = base(q) + er(Re p2) + ei(Im p2) with er/ei 4-point 1-D
// quadratics, so every bit-class min factorizes into 1-D partial mins
// (mag-class mins collapse to gA - |u|). All bit-class min reductions are
// wave-local: 12 butterfly channels, shuffle trees for sym0 low bits, one
// 16-float LDS pass for sym1 bits. yn term omitted (cancels in min0-min1).
__global__ __launch_bounds__(256) void mld_wave(
    const float* __restrict__ y_re, const float* __restrict__ y_im,
    const float* __restrict__ h_re, const float* __restrict__ h_im,
    const float* __restrict__ s_re, const float* __restrict__ s_im,
    float* __restrict__ out, int B) {
    int tid = threadIdx.x;
    int w = tid >> 6, lane = tid & 63;
    int b = blockIdx.x * 4 + w;
    bool live = (b < B);
    if (!live) b = B - 1;  // clamp: duplicate compute, stores suppressed

    __shared__ float s_xr[4][4][8], s_xi[4][4][8];  // [wave][col][row]
    __shared__ float s_w[4][16];                    // G (3 diag + 3 cplx), z (3 cplx)
    __shared__ float s16[4][16];                    // per-i1 mins

    // ---------------- Phase 1: cooperative Cholesky + solves (all 64 lanes) ----------------
    {
        int ii = lane >> 3, kk = lane & 7;  // lane owns matrix element (ii, kk)
        float ar = s_re[b * 64 + lane];     // coalesced 256B per wave
        float ai = s_im[b * 64 + lane];
        float br = 0.0f, bi = 0.0f;         // RHS column kk (kk<4): 0=y, 1..3=h cols
        if (kk == 0) {
            br = y_re[b * 8 + ii];
            bi = y_im[b * 8 + ii];
        } else if (kk < 4) {
            br = h_re[b * 24 + ii * 3 + (kk - 1)];
            bi = h_im[b * 24 + ii * 3 + (kk - 1)];
        }

        // Right-looking complex Cholesky (lower). v_rsq approx (~1e-7 rel) is
        // far inside the 2e-3 output tolerance and cuts the serial chain.
#pragma unroll
        for (int j = 0; j < 8; ++j) {
            float djr = __shfl(ar, j * 9, 64);  // A[j][j] (real)
            float dinv = __builtin_amdgcn_rsqf(djr);
            if (kk == j && ii >= j) { ar *= dinv; ai *= dinv; }
            float Lijr = __shfl(ar, ii * 8 + j, 64), Liji = __shfl(ai, ii * 8 + j, 64);
            float Lkjr = __shfl(ar, kk * 8 + j, 64), Lkji = __shfl(ai, kk * 8 + j, 64);
            if (kk > j && ii >= kk) {
                ar -= Lijr * Lkjr + Liji * Lkji;  // -= L[i][j]*conj(L[k][j])
                ai -= Liji * Lkjr - Lijr * Lkji;
            }
        }
        // Forward substitution L x = rhs, 4 columns at once.
#pragma unroll
        for (int k = 0; k < 8; ++k) {
            float dk = __shfl(ar, k * 9, 64);
            float dinvk = __builtin_amdgcn_rcpf(dk);
            if (ii == k) { br *= dinvk; bi *= dinvk; }
            float xkr = __shfl(br, k * 8 + kk, 64), xki = __shfl(bi, k * 8 + kk, 64);
            float Likr = __shfl(ar, ii * 8 + k, 64), Liki = __shfl(ai, ii * 8 + k, 64);
            if (ii > k) {
                br -= Likr * xkr - Liki * xki;
                bi -= Likr * xki + Liki * xkr;
            }
        }
        if (kk < 4) { s_xr[w][kk][ii] = br; s_xi[w][kk][ii] = bi; }
    }
    __syncthreads();

    // ---------------- Phase 1b: G (3x3 herm) and z (3) -> s_w ----------------
    if (lane < 9) {
        // pairs (pa,pc): lanes 0..2 diag |hw_c|^2; 3..5 g01,g02,g12; 6..8 z0,z1,z2
        int pa = (int)((0x000211321ull >> (lane * 4)) & 15ull);
        int pc = (int)((0x321332321ull >> (lane * 4)) & 15ull);
        float sr = 0.0f, si = 0.0f;
#pragma unroll
        for (int m = 0; m < 8; ++m) {
            float xar = s_xr[w][pa][m], xai = s_xi[w][pa][m];
            float xbr = s_xr[w][pc][m], xbi = s_xi[w][pc][m];
            sr += xar * xbr + xai * xbi;  // conj(xa)*xb
            si += xar * xbi - xai * xbr;
        }
        if (lane < 3) {
            s_w[w][lane] = sr;
        } else {
            int base2 = 3 + (lane - 3) * 2;
            s_w[w][base2] = sr;
            s_w[w][base2 + 1] = si;
        }
    }
    __syncthreads();

    // ---------------- Phase 2: candidate sweep (4 sign-combos/lane, separable i2) ----------------
    const float* ww = s_w[w];
    float g00 = ww[0], g11 = ww[1], g22 = ww[2];
    float g01r = ww[3], g01i = ww[4], g02r = ww[5], g02i = ww[6];
    float g12r = ww[7], g12i = ww[8];
    float z0r = ww[9], z0i = ww[10], z1r = ww[11], z1i = ww[12];
    float z2r = ww[13], z2i = ww[14];

    int a = lane >> 4, i1 = lane & 15;
    float p1r = QR(i1), p1i = QI(i1);
    float n1 = p1r * p1r + p1i * p1i;
    float a1c = g11 * n1 - 2.0f * (z1r * p1r - z1i * p1i);
    float w1r = g12r * p1r + g12i * p1i;  // g12*conj(p1)
    float w1i = g12i * p1r - g12r * p1i;
    float mr0 = (a & 2) ? 3.0f * RT10 : RT10;  // |Re p0|
    float mi0 = (a & 1) ? 3.0f * RT10 : RT10;  // |Im p0|
    float n0 = mr0 * mr0 + mi0 * mi0;

    // q-loop invariants. p0 = (sr*mr0, si*mi0), sr=(q&2)?-1:+1, si=(q&1)?-1:+1.
    // base(q) = C0 + sr*P + si*Q  (exact expansion of a0c + a1c + cross01)
    float C0 = fmaf(g00, n0, a1c);
    float P = 2.0f * mr0 * (g01r * p1r - g01i * p1i - z0r);
    float Q = 2.0f * mi0 * (g01r * p1i + g01i * p1r + z0i);
    // cr(q) = cw + sr*gr1 + si*gr2 ; ci(q) = cv - sr*gi1 + si*gi2
    float cw = 2.0f * (w1r - z2r);
    float cv = 2.0f * (z2i - w1i);
    float gr1 = 2.0f * g02r * mr0, gr2 = 2.0f * g02i * mi0;
    float gi1 = 2.0f * g02i * mr0, gi2 = 2.0f * g02r * mi0;
    // er(rho) = g22*rho^2 + rho*cr over rho in {+-1,+-3}*RT10: quad part
    float gA = 0.1f * g22, gB = 0.9f * g22;

    float ch[12];  // 0..7: sym2 bit n val v -> ch[n*2+v]; 8..11: sym0 bit3/bit2 classes
#pragma unroll
    for (int j = 0; j < 12; ++j) ch[j] = BIG;
    float u[4];
#pragma unroll
    for (int q = 0; q < 4; ++q) {
        // i0 = a | (q<<2): bit3=q>>1, bit2=q&1 (signs), bit1=a>>1, bit0=a&1 (mags)
        float base = C0 + ((q & 2) ? -P : P) + ((q & 1) ? -Q : Q);
        float cr = cw + ((q & 2) ? -gr1 : gr1) + ((q & 1) ? -gr2 : gr2);
        float ci = cv + ((q & 2) ? gi1 : -gi1) + ((q & 1) ? -gi2 : gi2);  // ci = cv - sr*gi1 + si*gi2
        float u1 = RT10 * cr, u3 = 3.0f * u1;
        float v1 = RT10 * ci, v3 = 3.0f * v1;
        // 1-D partial mins over Re(p2): sign classes and mag classes
        float minRp = fminf(gA + u1, gB + u3);   // i2 bit3 = 0 (sign +)
        float minRm = fminf(gA - u1, gB - u3);   // i2 bit3 = 1
        float minR1 = gA - fabsf(u1);            // i2 bit1 = 0 (mag 1)
        float minR3 = gB - fabsf(u3);            // i2 bit1 = 1 (mag 3)
        float minR = fminf(minR1, minR3);
        // 1-D partial mins over Im(p2)
        float minIp = fminf(gA + v1, gB + v3);   // i2 bit2 = 0
        float minIm = fminf(gA - v1, gB - v3);   // i2 bit2 = 1
        float minI1 = gA - fabsf(v1);            // i2 bit0 = 0
        float minI3 = gB - fabsf(v3);            // i2 bit0 = 1
        float minI = fminf(minI1, minI3);
        float sR = base + minR, sI = base + minI;
        ch[0] = fminf(ch[0], sI + minRp);
        ch[1] = fminf(ch[1], sI + minRm);
        ch[2] = fminf(ch[2], sR + minIp);
        ch[3] = fminf(ch[3], sR + minIm);
        ch[4] = fminf(ch[4], sI + minR1);
        ch[5] = fminf(ch[5], sI + minR3);
        ch[6] = fminf(ch[6], sR + minI1);
        ch[7] = fminf(ch[7], sR + minI3);
        u[q] = sR + minI;  // min over all 16 i2 for this (lane, q)
    }
    // sym0 high-bit classes (register dim q): bit3 = q>>1, bit2 = q&1
    ch[8] = fminf(u[0], u[1]);   // i0 bit3 = 0
    ch[9] = fminf(u[2], u[3]);   // i0 bit3 = 1
    ch[10] = fminf(u[0], u[2]);  // i0 bit2 = 0
    ch[11] = fminf(u[1], u[3]);  // i0 bit2 = 1

    // full-wave butterfly min of all 12 channels
#pragma unroll
    for (int j = 0; j < 12; ++j) {
        float v = ch[j];
#pragma unroll
        for (int mask = 1; mask < 64; mask <<= 1) v = fminf(v, __shfl_xor(v, mask, 64));
        ch[j] = v;
    }

    float t1 = fminf(fminf(u[0], u[1]), fminf(u[2], u[3]));  // min over q,i2 per (a,i1)
    float r0 = t1;  // -> min over i1 (lane bits 0..3), per a
#pragma unroll
    for (int mask = 1; mask <= 8; mask <<= 1) r0 = fminf(r0, __shfl_xor(r0, mask, 64));
    float r1 = fminf(t1, __shfl_xor(t1, 16, 64));  // -> min over a (lane bits 4,5), per i1
    r1 = fminf(r1, __shfl_xor(r1, 32, 64));
    if (lane < 16) s16[w][lane] = r1;

    // sym0 bit1 (= lane bit5) and bit0 (= lane bit4) classes from r0
    float zv = fminf(r0, __shfl_xor(r0, 16, 64));   // grouped by bit5
    float llr2 = zv - __shfl_xor(zv, 32, 64);       // valid at lanes with bit5=0
    float yv = fminf(r0, __shfl_xor(r0, 32, 64));   // grouped by bit4
    float llr3 = yv - __shfl_xor(yv, 16, 64);       // valid at lanes with bit4=0
    __syncthreads();  // s16 visibility

    // ---------------- Outputs: out[b*12 + k*4 + n], bit = (i_k >> (3-n)) & 1 ----------------
    if (live) {
        float* ob = out + b * 12;
        if (lane == 0) {
            ob[0] = ch[8] - ch[9];    // sym0 n=0 (bit3)
            ob[1] = ch[10] - ch[11];  // sym0 n=1 (bit2)
            ob[2] = llr2;             // sym0 n=2 (bit1)  [lane0: bit5=0 -> class0 resident]
            ob[3] = llr3;             // sym0 n=3 (bit0)  [lane0: bit4=0]
        } else if (lane >= 4 && lane < 8) {
            int k = 3 - (lane - 4);   // sym1 bit index
            float m0 = BIG, m1 = BIG;
#pragma unroll
            for (int j = 0; j < 16; ++j) {
                float v = s16[w][j];  // broadcast reads
                if ((j >> k) & 1) m1 = fminf(m1, v);
                else m0 = fminf(m0, v);
            }
            ob[lane] = m0 - m1;
        } else if (lane >= 8 && lane < 12) {
            int n = lane - 8;         // sym2 bits from butterflied channels
            ob[lane] = ch[n * 2] - ch[n * 2 + 1];
        }
    }
}

extern "C" void kernel_launch(void* const* d_in, const int* in_sizes, int n_in,
                              void* d_out, int out_size, void* d_ws, size_t ws_size,
                              hipStream_t stream) {
    const float* y_re = (const float*)d_in[0];
    const float* y_im = (const float*)d_in[1];
    const float* h_re = (const float*)d_in[2];
    const float* h_im = (const float*)d_in[3];
    const float* s_re = (const float*)d_in[4];
    const float* s_im = (const float*)d_in[5];
    int B = in_sizes[0] / 8;  // M = 8

    mld_wave<<<dim3((B + 3) / 4), dim3(256), 0, stream>>>(y_re, y_im, h_re, h_im,
                                                          s_re, s_im, (float*)d_out, B);
}